// Round 5
// baseline (342.286 us; speedup 1.0000x reference)
//
#include <hip/hip_runtime.h>

typedef unsigned short u16;
typedef unsigned int u32;
typedef __attribute__((ext_vector_type(8))) short bf16x8;
typedef __attribute__((ext_vector_type(4))) float f32x4;
typedef __attribute__((ext_vector_type(2))) unsigned int u32x2;

#define LOG2E 1.4426950408889634f

__device__ __forceinline__ u16 f2bf(float f) {
    u32 u = __float_as_uint(f);
    u += 0x7fffu + ((u >> 16) & 1u);
    return (u16)(u >> 16);
}
__device__ __forceinline__ float bf2f(u16 s) {
    return __uint_as_float(((u32)s) << 16);
}
// pack two f32 -> two truncated bf16 in one v_perm (hi in bits 31:16, lo in 15:0)
__device__ __forceinline__ u32 pk_bf_trunc(float hi, float lo) {
    return __builtin_amdgcn_perm(__float_as_uint(hi), __float_as_uint(lo), 0x07060302u);
}

// ---------------- Kernel 0: weight prep ----------------
// blocks 0..63: wbf[mat][n][k]: mats 0..3 = {Wq,Wk,Wv,Wg}*norm_w[k] (bf16), mat 4 = Wo.
// blocks 64..67: cvec[m*128+n] = sum_k norm_b[k]*W_m[n,k]  (+bg[n] for m==3 gate).
__global__ void wconv_kernel(const float* __restrict__ Wq, const float* __restrict__ Wk,
                             const float* __restrict__ Wv, const float* __restrict__ Wg,
                             const float* __restrict__ Wo, const float* __restrict__ norm_w,
                             const float* __restrict__ norm_b, const float* __restrict__ bg,
                             u16* __restrict__ wbf, float* __restrict__ cvec) {
    int b = blockIdx.x;
    if (b < 64) {
        int idx = b * 256 + threadIdx.x;  // 0..16383
        float w = norm_w[idx & 127];
        wbf[0 * 16384 + idx] = f2bf(Wq[idx] * w);
        wbf[1 * 16384 + idx] = f2bf(Wk[idx] * w);
        wbf[2 * 16384 + idx] = f2bf(Wv[idx] * w);
        wbf[3 * 16384 + idx] = f2bf(Wg[idx] * w);
        wbf[4 * 16384 + idx] = f2bf(Wo[idx]);
    } else {
        int m = b - 64;
        int n = threadIdx.x;
        if (n < 128) {
            const float* W = (m == 0) ? Wq : (m == 1) ? Wk : (m == 2) ? Wv : Wg;
            float c = 0.f;
#pragma unroll
            for (int k4 = 0; k4 < 32; ++k4) {
                f32x4 bb = *(const f32x4*)&norm_b[k4 * 4];
                f32x4 ww = *(const f32x4*)&W[n * 128 + k4 * 4];
                c += bb[0] * ww[0] + bb[1] * ww[1] + bb[2] * ww[2] + bb[3] * ww[3];
            }
            if (m == 3) c += bg[n];
            cvec[m * 128 + n] = c;
        }
    }
}

// ---------------- Kernel 1: fused LN + QKVG projection + attention ----------------
// Grid 640 = (l, head-pair). 512 threads = 8 waves, 1 block/CU (LDS ~155 KB).
// smem u16 map:
//   [0, 9216)       : Phase-B per-wave P buffers (8 x 1152); aliases Phase-A Xs [0, 8704)
//   [9216, 29696)   : QALL: 40 (strip,head) x 16x32 transposed Q tiles (512 u16 each)
//   [29696, 55296)  : KS: 2 heads x 320x40
//   [55296, 76288)  : VTS: 2 heads x 32x328
#define PB_W 1152
#define QALL_OFF 9216
#define KS_OFF 29696
#define VTS_OFF 55296

__global__ __launch_bounds__(512, 2)
void attn_kernel(const float* __restrict__ pair,
                 const float* __restrict__ Wb,
                 const u16* __restrict__ wbf,
                 const float* __restrict__ cvec,
                 u16* __restrict__ Obf,
                 u16* __restrict__ Gg) {
    const int l = blockIdx.x >> 1;
    const int hp = blockIdx.x & 1;  // head pair: heads hp*2, hp*2+1
    const int tid = threadIdx.x;
    const int wave = tid >> 6;
    const int lane = tid & 63;
    const int i_lo = lane & 15;
    const int q = lane >> 4;

    __shared__ __align__(16) u16 smem[76288];
    __shared__ __align__(16) float biasLds[640];  // per head: bias[j] * log2e

    const int row_g = tid >> 3;        // 0..63 (8 lanes per row)
    const int c8 = tid & 7;            // 16-col octant
    const int wrow = (wave & 3) * 16;  // row strip within 64-row tile
    const int nth_flip = wave >> 2;

    // Wb rows for both heads (raw-pair bias), register-resident
    f32x4 wbv[2][4];
#pragma unroll
    for (int hh = 0; hh < 2; ++hh)
#pragma unroll
        for (int u = 0; u < 4; ++u)
            wbv[hh][u] = *(const f32x4*)&Wb[(hp * 2 + hh) * 128 + c8 * 16 + u * 4];

    // folded biases for this lane's output columns (n depends on i_lo only)
    float cQ[4], cK[4], cV[4], cG[4];
#pragma unroll
    for (int e = 0; e < 4; ++e) {
        int n = (hp * 2 + (e >> 1)) * 32 + (e & 1) * 16 + i_lo;
        cQ[e] = cvec[0 * 128 + n];
        cK[e] = cvec[1 * 128 + n];
        cV[e] = cvec[2 * 128 + n];
        cG[e] = cvec[3 * 128 + n];
    }

    // ---------- Phase A: LN + projections, 5 tiles of 64 rows ----------
#pragma unroll 1
    for (int t = 0; t < 5; ++t) {
        const int j0 = t * 64;
        const float* prow = pair + ((size_t)(l * 320 + j0 + row_g)) * 128 + c8 * 16;
        f32x4 pr[4];
#pragma unroll
        for (int u = 0; u < 4; ++u) pr[u] = *(const f32x4*)(prow + u * 4);

        float s = 0.f, s2 = 0.f, bd0 = 0.f, bd1 = 0.f;
#pragma unroll
        for (int u = 0; u < 4; ++u) {
            f32x4 p = pr[u];
            s += p[0] + p[1] + p[2] + p[3];
            s2 += p[0] * p[0] + p[1] * p[1] + p[2] * p[2] + p[3] * p[3];
            f32x4 w0 = wbv[0][u], w1 = wbv[1][u];
            bd0 += p[0] * w0[0] + p[1] * w0[1] + p[2] * w0[2] + p[3] * w0[3];
            bd1 += p[0] * w1[0] + p[1] * w1[1] + p[2] * w1[2] + p[3] * w1[3];
        }
        s += __shfl_xor(s, 1);     s += __shfl_xor(s, 2);     s += __shfl_xor(s, 4);
        s2 += __shfl_xor(s2, 1);   s2 += __shfl_xor(s2, 2);   s2 += __shfl_xor(s2, 4);
        bd0 += __shfl_xor(bd0, 1); bd0 += __shfl_xor(bd0, 2); bd0 += __shfl_xor(bd0, 4);
        bd1 += __shfl_xor(bd1, 1); bd1 += __shfl_xor(bd1, 2); bd1 += __shfl_xor(bd1, 4);
        float mu = s * 0.0078125f;
        float var = s2 * 0.0078125f - mu * mu;
        float rs = rsqrtf(var + 1e-5f);

        __syncthreads();  // previous tile's Xs reads done
#pragma unroll
        for (int u = 0; u < 4; ++u) {
            f32x4 p = pr[u];
            ushort4 xv;
            xv.x = f2bf((p[0] - mu) * rs);
            xv.y = f2bf((p[1] - mu) * rs);
            xv.z = f2bf((p[2] - mu) * rs);
            xv.w = f2bf((p[3] - mu) * rs);
            *(ushort4*)&smem[row_g * 136 + c8 * 16 + u * 4] = xv;
        }
        if (c8 == 0) {
            biasLds[j0 + row_g] = bd0 * LOG2E;
            biasLds[320 + j0 + row_g] = bd1 * LOG2E;
        }
        __syncthreads();

        // wave does (Q,K) or (V,G) for BOTH heads on rows [wrow, wrow+16)
        const int nth = (t & 1) ^ nth_flip;  // 0 -> Q,K ; 1 -> V,G
        const int m0 = nth * 2;              // first mat (Q or V)
        f32x4 acc[8];
#pragma unroll
        for (int e = 0; e < 8; ++e) acc[e] = (f32x4){0.f, 0.f, 0.f, 0.f};
#pragma unroll
        for (int kc = 0; kc < 4; ++kc) {
            bf16x8 a = *(const bf16x8*)&smem[(wrow + i_lo) * 136 + kc * 32 + q * 8];
#pragma unroll
            for (int e = 0; e < 4; ++e) {
                int n = (hp * 2 + (e >> 1)) * 32 + (e & 1) * 16 + i_lo;
                bf16x8 wfa = *(const bf16x8*)&wbf[m0 * 16384 + n * 128 + kc * 32 + q * 8];
                acc[e] = __builtin_amdgcn_mfma_f32_16x16x32_bf16(a, wfa, acc[e], 0, 0, 0);
                bf16x8 wfb = *(const bf16x8*)&wbf[(m0 + 1) * 16384 + n * 128 + kc * 32 + q * 8];
                acc[4 + e] = __builtin_amdgcn_mfma_f32_16x16x32_bf16(a, wfb, acc[4 + e], 0, 0, 0);
            }
        }
        const int strip = t * 4 + (wave & 3);
        const int jrow = j0 + wrow + q * 4;
        if (nth == 0) {
#pragma unroll
            for (int e = 0; e < 4; ++e) {
                int head = e >> 1, half = e & 1;
                // Q -> transposed LDS tile for (strip, head)
                int qb = QALL_OFF + (strip * 2 + head) * 512;
#pragma unroll
                for (int r = 0; r < 4; ++r)
                    smem[qb + (q * 4 + r) * 32 + half * 16 + i_lo] = f2bf(acc[e][r] + cQ[e]);
                // K -> KS[head][j][d]
#pragma unroll
                for (int r = 0; r < 4; ++r)
                    smem[KS_OFF + head * 12800 + (jrow + r) * 40 + half * 16 + i_lo] =
                        f2bf(acc[4 + e][r] + cK[e]);
            }
        } else {
#pragma unroll
            for (int e = 0; e < 4; ++e) {
                int head = e >> 1, half = e & 1;
                // V -> VTS[head][d][j]
#pragma unroll
                for (int r = 0; r < 4; ++r)
                    smem[VTS_OFF + head * 10496 + (half * 16 + i_lo) * 328 + jrow + r] =
                        f2bf(acc[e][r] + cV[e]);
                // G -> global (gate applied in outproj); sigmoid with folded bias
#pragma unroll
                for (int r = 0; r < 4; ++r) {
                    float z = acc[4 + e][r] + cG[e];
                    float g = 1.0f / (1.0f + exp2f(-z * LOG2E));
                    Gg[((size_t)((l * 4 + hp * 2 + head) * 320 + jrow + r)) * 32 +
                       half * 16 + i_lo] = f2bf(g);
                }
            }
        }
    }
    __syncthreads();  // QALL/KS/VTS/bias visible; Xs region free for P buffers

    // ---------- Phase B: 40 (strip,head) tasks; wave w -> g = w + 8*t2, t2=0..4 ----------
    const float SC = 0.17677669529663687f * LOG2E;  // Dh^-0.5 * log2e
    const f32x4 zero4 = {0.f, 0.f, 0.f, 0.f};
    u16* pb = smem + wave * PB_W;
#pragma unroll 1
    for (int t2 = 0; t2 < 5; ++t2) {
        const int g = wave + 8 * t2;
        const int strip = g >> 1;
        const int hh = g & 1;
        const int i0 = strip * 16;
        bf16x8 qf = *(const bf16x8*)&smem[QALL_OFF + g * 512 + i_lo * 32 + q * 8];

        f32x4 oacc[2];
        oacc[0] = zero4; oacc[1] = zero4;
        float sum = 0.f;
        // 5 chunks of 64 j: S^T=K*Q^T -> exp -> P to pb -> O^T += V^T*P
#pragma unroll 1
        for (int c = 0; c < 5; ++c) {
            f32x4 sc4[4];
#pragma unroll
            for (int jt = 0; jt < 4; ++jt) {
                bf16x8 kf = *(const bf16x8*)&smem[KS_OFF + hh * 12800 +
                                                  (c * 64 + jt * 16 + i_lo) * 40 + q * 8];
                sc4[jt] = __builtin_amdgcn_mfma_f32_16x16x32_bf16(kf, qf, zero4, 0, 0, 0);
            }
#pragma unroll
            for (int jt = 0; jt < 4; ++jt) {
                f32x4 b4 = *(const f32x4*)&biasLds[hh * 320 + c * 64 + jt * 16 + q * 4];
#pragma unroll
                for (int r = 0; r < 4; ++r) {
                    float p = exp2f(sc4[jt][r] * SC + b4[r]);
                    sc4[jt][r] = p;
                    sum += p;
                }
            }
#pragma unroll
            for (int jt = 0; jt < 4; ++jt) {
                u32x2 pk;
                pk.x = pk_bf_trunc(sc4[jt][1], sc4[jt][0]);
                pk.y = pk_bf_trunc(sc4[jt][3], sc4[jt][2]);
                *(u32x2*)&pb[i_lo * 72 + jt * 16 + q * 4] = pk;
            }
#pragma unroll
            for (int kt2 = 0; kt2 < 2; ++kt2) {
                bf16x8 pf = *(const bf16x8*)&pb[i_lo * 72 + kt2 * 32 + q * 8];
#pragma unroll
                for (int mt = 0; mt < 2; ++mt) {
                    bf16x8 vf = *(const bf16x8*)&smem[VTS_OFF + hh * 10496 +
                                                      (mt * 16 + i_lo) * 328 + c * 64 +
                                                      kt2 * 32 + q * 8];
                    oacc[mt] = __builtin_amdgcn_mfma_f32_16x16x32_bf16(vf, pf, oacc[mt], 0, 0, 0);
                }
            }
        }
        sum += __shfl_xor(sum, 16);
        sum += __shfl_xor(sum, 32);
        float rinv = 1.0f / sum;
        // lane holds O^T[d = mt*16+q*4+r][i = i0+i_lo]; normalize, store (gate in outproj)
#pragma unroll
        for (int mt = 0; mt < 2; ++mt) {
            u32x2 pk;
            pk.x = pk_bf_trunc(oacc[mt][1] * rinv, oacc[mt][0] * rinv);
            pk.y = pk_bf_trunc(oacc[mt][3] * rinv, oacc[mt][2] * rinv);
            *(u32x2*)&Obf[((size_t)(l * 320 + i0 + i_lo)) * 128 +
                          (hp * 2 + hh) * 32 + mt * 16 + q * 4] = pk;
        }
    }
}

// ---------------- Kernel 2: out = pair + (g .* O) @ Wo^T + bo ----------------
// LDS-staged epilogue: stores/loads are full 128B row segments (coalesced).
__global__ __launch_bounds__(256)
void outproj_kernel(const float* __restrict__ pair,
                    const float* __restrict__ bo,
                    const u16* __restrict__ Obf,
                    const u16* __restrict__ Gg,
                    const u16* __restrict__ wbf,
                    float* __restrict__ out) {
    const int tid = threadIdx.x;
    const int wave = tid >> 6;
    const int lane = tid & 63;
    const int i_lo = lane & 15;
    const int q = lane >> 4;
    const int blk = blockIdx.x;
    const int mrow = blk * 64 + wave * 16;
    const int lidx = blk / 5;                   // 64-row blocks never straddle l
    const int irow = mrow - lidx * 320 + i_lo;  // row within l
    const u16* Wo = wbf + 4 * 16384;

    __shared__ __align__(16) float ot[4][16 * 133];

    // A-frag = O .* g (elementwise bf16; kc = head)
    bf16x8 of[4];
#pragma unroll
    for (int kc = 0; kc < 4; ++kc) {
        union { bf16x8 v; u32 u[4]; } A, G, R;
        A.v = *(const bf16x8*)&Obf[((size_t)(mrow + i_lo)) * 128 + kc * 32 + q * 8];
        G.v = *(const bf16x8*)&Gg[((size_t)((lidx * 4 + kc) * 320 + irow)) * 32 + q * 8];
#pragma unroll
        for (int k4 = 0; k4 < 4; ++k4) {
            float lo = __uint_as_float(A.u[k4] << 16) * __uint_as_float(G.u[k4] << 16);
            float hi = __uint_as_float(A.u[k4] & 0xffff0000u) * __uint_as_float(G.u[k4] & 0xffff0000u);
            R.u[k4] = pk_bf_trunc(hi, lo);
        }
        of[kc] = R.v;
    }

    f32x4 acc[8];
#pragma unroll
    for (int nt = 0; nt < 8; ++nt) acc[nt] = (f32x4){0.f, 0.f, 0.f, 0.f};
#pragma unroll
    for (int nt = 0; nt < 8; ++nt) {
#pragma unroll
        for (int kc = 0; kc < 4; ++kc) {
            bf16x8 wf = *(const bf16x8*)&Wo[(nt * 16 + i_lo) * 128 + kc * 32 + q * 8];
            acc[nt] = __builtin_amdgcn_mfma_f32_16x16x32_bf16(wf, of[kc], acc[nt], 0, 0, 0);
        }
    }
    // stage: lane holds out[row = i_lo][col = nt*16 + q*4 + r] of the wave's 16x128 tile
#pragma unroll
    for (int nt = 0; nt < 8; ++nt)
        *(f32x4*)&ot[wave][i_lo * 133 + nt * 16 + q * 4] = acc[nt];
    __syncthreads();

    const int r8 = lane >> 3;
    const int c8i = lane & 7;
    f32x4 bo4[4];
#pragma unroll
    for (int k = 0; k < 4; ++k) bo4[k] = *(const f32x4*)&bo[k * 32 + c8i * 4];
#pragma unroll
    for (int u = 0; u < 2; ++u) {
        int lr = u * 8 + r8;
        size_t rbase = ((size_t)(mrow + lr)) * 128;
#pragma unroll
        for (int k = 0; k < 4; ++k) {
            int col = k * 32 + c8i * 4;
            f32x4 v = *(const f32x4*)&ot[wave][lr * 133 + col];
            f32x4 p4 = *(const f32x4*)&pair[rbase + col];
            f32x4 o4;
            o4[0] = v[0] + p4[0] + bo4[k][0];
            o4[1] = v[1] + p4[1] + bo4[k][1];
            o4[2] = v[2] + p4[2] + bo4[k][2];
            o4[3] = v[3] + p4[3] + bo4[k][3];
            *(f32x4*)&out[rbase + col] = o4;
        }
    }
}

extern "C" void kernel_launch(void* const* d_in, const int* in_sizes, int n_in,
                              void* d_out, int out_size, void* d_ws, size_t ws_size,
                              hipStream_t stream) {
    const float* pair   = (const float*)d_in[0];
    const float* norm_w = (const float*)d_in[1];
    const float* norm_b = (const float*)d_in[2];
    const float* Wq     = (const float*)d_in[3];
    const float* Wk     = (const float*)d_in[4];
    const float* Wv     = (const float*)d_in[5];
    const float* Wg     = (const float*)d_in[6];
    const float* bg     = (const float*)d_in[7];
    const float* Wo     = (const float*)d_in[8];
    const float* bo     = (const float*)d_in[9];
    const float* Wb     = (const float*)d_in[10];

    u16* wbf   = (u16*)d_ws;                    // 5 * 128*128 bf16 weights (160 KB)
    float* cvec = (float*)(wbf + 5 * 16384);    // 512 f32 folded biases (2 KB)
    u16* Obf   = (u16*)(cvec + 512);            // 102400 x 128 bf16 (ungated, normalized)
    u16* Gg    = Obf + (size_t)102400 * 128;    // (l,h,i,d) 1280 x 320 x 32 bf16 gates
    float* out = (float*)d_out;

    wconv_kernel<<<68, 256, 0, stream>>>(Wq, Wk, Wv, Wg, Wo, norm_w, norm_b, bg, wbf, cvec);
    attn_kernel<<<320 * 2, 512, 0, stream>>>(pair, Wb, wbf, cvec, Obf, Gg);
    outproj_kernel<<<1600, 256, 0, stream>>>(pair, bo, Obf, Gg, wbf, out);
}

// Round 6
// 281.060 us; speedup vs baseline: 1.2178x; 1.2178x over previous
//
#include <hip/hip_runtime.h>

typedef unsigned short u16;
typedef unsigned int u32;
typedef __attribute__((ext_vector_type(8))) short bf16x8;
typedef __attribute__((ext_vector_type(4))) float f32x4;
typedef __attribute__((ext_vector_type(2))) unsigned int u32x2;

#define LOG2E 1.4426950408889634f

__device__ __forceinline__ u16 f2bf(float f) {
    u32 u = __float_as_uint(f);
    u += 0x7fffu + ((u >> 16) & 1u);
    return (u16)(u >> 16);
}
// pack two f32 -> two truncated bf16 in one v_perm (hi in bits 31:16, lo in 15:0)
__device__ __forceinline__ u32 pk_bf_trunc(float hi, float lo) {
    return __builtin_amdgcn_perm(__float_as_uint(hi), __float_as_uint(lo), 0x07060302u);
}

// ---------------- Kernel 0: weight prep ----------------
// blocks 0..63: wbf[mat][n][k]: mats 0..3 = {Wq,Wk,Wv,Wg}*norm_w[k] (bf16), mat 4 = Wo.
// blocks 64..67: cvec[m*128+n] = sum_k norm_b[k]*W_m[n,k]  (+bg[n] for m==3 gate).
__global__ void wconv_kernel(const float* __restrict__ Wq, const float* __restrict__ Wk,
                             const float* __restrict__ Wv, const float* __restrict__ Wg,
                             const float* __restrict__ Wo, const float* __restrict__ norm_w,
                             const float* __restrict__ norm_b, const float* __restrict__ bg,
                             u16* __restrict__ wbf, float* __restrict__ cvec) {
    int b = blockIdx.x;
    if (b < 64) {
        int idx = b * 256 + threadIdx.x;  // 0..16383
        float w = norm_w[idx & 127];
        wbf[0 * 16384 + idx] = f2bf(Wq[idx] * w);
        wbf[1 * 16384 + idx] = f2bf(Wk[idx] * w);
        wbf[2 * 16384 + idx] = f2bf(Wv[idx] * w);
        wbf[3 * 16384 + idx] = f2bf(Wg[idx] * w);
        wbf[4 * 16384 + idx] = f2bf(Wo[idx]);
    } else {
        int m = b - 64;
        int n = threadIdx.x;
        if (n < 128) {
            const float* W = (m == 0) ? Wq : (m == 1) ? Wk : (m == 2) ? Wv : Wg;
            float c = 0.f;
#pragma unroll
            for (int k4 = 0; k4 < 32; ++k4) {
                f32x4 bb = *(const f32x4*)&norm_b[k4 * 4];
                f32x4 ww = *(const f32x4*)&W[n * 128 + k4 * 4];
                c += bb[0] * ww[0] + bb[1] * ww[1] + bb[2] * ww[2] + bb[3] * ww[3];
            }
            if (m == 3) c += bg[n];
            cvec[m * 128 + n] = c;
        }
    }
}

// ---------------- Kernel 1: fused LN + QKVG projection + attention ----------------
// Grid 1280 = (l, h). 512 threads = 8 waves, LDS ~66 KB -> 2 blocks/CU.
// smem u16 layout:
//   [0, 9216)      : UNION  Phase A Xs (64x136=8704)  /  Phase B per-wave bufs (8 x 1152)
//   [9216, 22016)  : Ks 320x40
//   [22016, 32576) : VTs 32x330 (pad 330: conflict-free scatter writes)
#define KS_OFF 9216
#define VTS_OFF 22016
#define PB_W 1152   // per-wave: Q-transpose (16x40) then P-chunks (16x72)

__global__ __launch_bounds__(512, 4)
void attn_kernel(const float* __restrict__ pair,
                 const float* __restrict__ Wb,
                 const u16* __restrict__ wbf,
                 const float* __restrict__ cvec,
                 u16* __restrict__ Obf,
                 u16* __restrict__ Gg) {
    const int l = blockIdx.x >> 2;
    const int h = blockIdx.x & 3;
    const int tid = threadIdx.x;
    const int wave = tid >> 6;
    const int lane = tid & 63;
    const int i_lo = lane & 15;
    const int q = lane >> 4;

    __shared__ __align__(16) u16 smem[32576];
    __shared__ __align__(16) float biasLds[320];  // bias[j] * log2e

    const int row_g = tid >> 3;        // 0..63 (8 lanes per row)
    const int c8 = tid & 7;            // 16-col octant
    const int wrow = (wave & 3) * 16;  // MFMA row strip within tile
    const int nth_flip = wave >> 2;    // wave does Q,K on tiles with t&1 == wave>>2

    // Wb row for this head (raw-pair bias), register-resident
    f32x4 wbv[4];
#pragma unroll
    for (int u = 0; u < 4; ++u)
        wbv[u] = *(const f32x4*)&Wb[h * 128 + c8 * 16 + u * 4];

    // folded biases for this lane's output channels (halves 0/1)
    float cQ[2], cK[2], cV[2], cG[2];
#pragma unroll
    for (int half = 0; half < 2; ++half) {
        int n = h * 32 + half * 16 + i_lo;
        cQ[half] = cvec[0 * 128 + n];
        cK[half] = cvec[1 * 128 + n];
        cV[half] = cvec[2 * 128 + n];
        cG[half] = cvec[3 * 128 + n];
    }

    u32 qkeep[3][4];  // per-strip Q fragment, packed bf16

    // ---------- Phase A: LN + projections, 5 tiles of 64 rows ----------
#pragma unroll 1
    for (int t = 0; t < 5; ++t) {
        const int j0 = t * 64;
        const float* prow = pair + ((size_t)(l * 320 + j0 + row_g)) * 128 + c8 * 16;
        f32x4 pr[4];
#pragma unroll
        for (int u = 0; u < 4; ++u) pr[u] = *(const f32x4*)(prow + u * 4);

        float s = 0.f, s2 = 0.f, bd = 0.f;
#pragma unroll
        for (int u = 0; u < 4; ++u) {
            f32x4 p = pr[u];
            f32x4 wb4 = wbv[u];
            s += p[0] + p[1] + p[2] + p[3];
            s2 += p[0] * p[0] + p[1] * p[1] + p[2] * p[2] + p[3] * p[3];
            bd += p[0] * wb4[0] + p[1] * wb4[1] + p[2] * wb4[2] + p[3] * wb4[3];
        }
        s += __shfl_xor(s, 1);   s += __shfl_xor(s, 2);   s += __shfl_xor(s, 4);
        s2 += __shfl_xor(s2, 1); s2 += __shfl_xor(s2, 2); s2 += __shfl_xor(s2, 4);
        bd += __shfl_xor(bd, 1); bd += __shfl_xor(bd, 2); bd += __shfl_xor(bd, 4);
        float mu = s * 0.0078125f;
        float var = s2 * 0.0078125f - mu * mu;
        float rs = rsqrtf(var + 1e-5f);

        __syncthreads();  // previous tile's Xs reads done
#pragma unroll
        for (int u = 0; u < 4; ++u) {
            f32x4 p = pr[u];
            ushort4 xv;
            xv.x = f2bf((p[0] - mu) * rs);
            xv.y = f2bf((p[1] - mu) * rs);
            xv.z = f2bf((p[2] - mu) * rs);
            xv.w = f2bf((p[3] - mu) * rs);
            *(ushort4*)&smem[row_g * 136 + c8 * 16 + u * 4] = xv;
        }
        if (c8 == 0) biasLds[j0 + row_g] = bd * LOG2E;
        __syncthreads();

        // projection: wave does (Q,K) or (V,G) half for rows [wrow, wrow+16)
        const int nth = (t & 1) ^ nth_flip;
        f32x4 acc[4];
#pragma unroll
        for (int n2 = 0; n2 < 4; ++n2) acc[n2] = (f32x4){0.f, 0.f, 0.f, 0.f};
#pragma unroll
        for (int kc = 0; kc < 4; ++kc) {
            bf16x8 a = *(const bf16x8*)&smem[(wrow + i_lo) * 136 + kc * 32 + q * 8];
#pragma unroll
            for (int n2 = 0; n2 < 4; ++n2) {
                int nt = nth * 4 + n2;  // 0,1=Q 2,3=K 4,5=V 6,7=G
                bf16x8 wf = *(const bf16x8*)&wbf[(nt >> 1) * 16384 +
                                                 (h * 32 + (nt & 1) * 16 + i_lo) * 128 + kc * 32 + q * 8];
                acc[n2] = __builtin_amdgcn_mfma_f32_16x16x32_bf16(a, wf, acc[n2], 0, 0, 0);
            }
        }
        const int jrow = j0 + wrow + q * 4;
        if (nth == 0) {
            const int ti = t >> 1;  // strip index for this wave
#pragma unroll
            for (int dd = 0; dd < 2; ++dd)
#pragma unroll
                for (int rr = 0; rr < 2; ++rr)
                    qkeep[ti][dd * 2 + rr] =
                        (u32)f2bf(acc[dd][rr * 2] + cQ[dd]) |
                        ((u32)f2bf(acc[dd][rr * 2 + 1] + cQ[dd]) << 16);
#pragma unroll
            for (int n2 = 2; n2 < 4; ++n2)
#pragma unroll
                for (int r = 0; r < 4; ++r)
                    smem[KS_OFF + (jrow + r) * 40 + (n2 & 1) * 16 + i_lo] =
                        f2bf(acc[n2][r] + cK[n2 & 1]);
        } else {
#pragma unroll
            for (int n2 = 0; n2 < 2; ++n2)
#pragma unroll
                for (int r = 0; r < 4; ++r)
                    smem[VTS_OFF + (n2 * 16 + i_lo) * 330 + jrow + r] =
                        f2bf(acc[n2][r] + cV[n2]);
#pragma unroll
            for (int n2 = 2; n2 < 4; ++n2)
#pragma unroll
                for (int r = 0; r < 4; ++r) {
                    float z = acc[n2][r] + cG[n2 & 1];
                    float g = 1.0f / (1.0f + exp2f(-z * LOG2E));
                    Gg[((size_t)((l * 4 + h) * 320 + jrow + r)) * 32 + (n2 & 1) * 16 + i_lo] = f2bf(g);
                }
        }
    }
    __syncthreads();  // Ks/VTs/bias visible; Xs region free for per-wave buffers

    // ---------- Phase B: wave w handles strips w, w+8, w+16(w<4) ----------
    const float SC = 0.17677669529663687f * LOG2E;  // Dh^-0.5 * log2e
    const f32x4 zero4 = {0.f, 0.f, 0.f, 0.f};
    u16* pb = smem + wave * PB_W;
    const int nstrip = (wave < 4) ? 3 : 2;
#pragma unroll 1
    for (int t2 = 0; t2 < nstrip; ++t2) {
        const int i0 = (wave + 8 * t2) * 16;
        // Q transpose: C-layout regs -> pb[i][d] (stride 40) -> B-frag read
#pragma unroll
        for (int dd = 0; dd < 2; ++dd)
#pragma unroll
            for (int rr = 0; rr < 2; ++rr) {
                u32 v = qkeep[t2][dd * 2 + rr];
                pb[(q * 4 + rr * 2) * 40 + dd * 16 + i_lo] = (u16)v;
                pb[(q * 4 + rr * 2 + 1) * 40 + dd * 16 + i_lo] = (u16)(v >> 16);
            }
        bf16x8 qf = *(const bf16x8*)&pb[i_lo * 40 + q * 8];

        f32x4 oacc[2];
        oacc[0] = zero4; oacc[1] = zero4;
        float sum = 0.f;
        // 5 chunks of 64 j: S^T=K*Q^T -> exp -> P to pb -> O^T += V^T*P
#pragma unroll 1
        for (int c = 0; c < 5; ++c) {
            f32x4 sc4[4];
#pragma unroll
            for (int jt = 0; jt < 4; ++jt) {
                bf16x8 kf = *(const bf16x8*)&smem[KS_OFF + (c * 64 + jt * 16 + i_lo) * 40 + q * 8];
                sc4[jt] = __builtin_amdgcn_mfma_f32_16x16x32_bf16(kf, qf, zero4, 0, 0, 0);
            }
#pragma unroll
            for (int jt = 0; jt < 4; ++jt) {
                f32x4 b4 = *(const f32x4*)&biasLds[c * 64 + jt * 16 + q * 4];
#pragma unroll
                for (int r = 0; r < 4; ++r) {
                    float p = exp2f(sc4[jt][r] * SC + b4[r]);
                    sc4[jt][r] = p;
                    sum += p;
                }
            }
#pragma unroll
            for (int jt = 0; jt < 4; ++jt) {
                u32x2 pk;
                pk.x = pk_bf_trunc(sc4[jt][1], sc4[jt][0]);
                pk.y = pk_bf_trunc(sc4[jt][3], sc4[jt][2]);
                *(u32x2*)&pb[i_lo * 72 + jt * 16 + q * 4] = pk;
            }
#pragma unroll
            for (int kt2 = 0; kt2 < 2; ++kt2) {
                bf16x8 pf = *(const bf16x8*)&pb[i_lo * 72 + kt2 * 32 + q * 8];
#pragma unroll
                for (int mt = 0; mt < 2; ++mt) {
                    bf16x8 vf = *(const bf16x8*)&smem[VTS_OFF + (mt * 16 + i_lo) * 330 +
                                                      c * 64 + kt2 * 32 + q * 8];
                    oacc[mt] = __builtin_amdgcn_mfma_f32_16x16x32_bf16(vf, pf, oacc[mt], 0, 0, 0);
                }
            }
        }
        sum += __shfl_xor(sum, 16);
        sum += __shfl_xor(sum, 32);
        float rinv = 1.0f / sum;
        // lane holds O^T[d = mt*16+q*4+r][i = i0+i_lo]; normalize, store (gate in outproj)
#pragma unroll
        for (int mt = 0; mt < 2; ++mt) {
            u32x2 pk;
            pk.x = pk_bf_trunc(oacc[mt][1] * rinv, oacc[mt][0] * rinv);
            pk.y = pk_bf_trunc(oacc[mt][3] * rinv, oacc[mt][2] * rinv);
            *(u32x2*)&Obf[((size_t)(l * 320 + i0 + i_lo)) * 128 + h * 32 + mt * 16 + q * 4] = pk;
        }
    }
}

// ---------------- Kernel 2: out = pair + (g .* O) @ Wo^T + bo ----------------
// 512 threads / 8 waves, 128 rows per block (grid 800). Wo staged in padded LDS.
__global__ __launch_bounds__(512, 6)
void outproj_kernel(const float* __restrict__ pair,
                    const float* __restrict__ bo,
                    const u16* __restrict__ Obf,
                    const u16* __restrict__ Gg,
                    const u16* __restrict__ wbf,
                    float* __restrict__ out) {
    const int tid = threadIdx.x;
    const int wave = tid >> 6;
    const int lane = tid & 63;
    const int i_lo = lane & 15;
    const int q = lane >> 4;

    __shared__ __align__(16) u16 WoLds[128 * 132];  // pad 132: conflict-free frag reads
    const u16* Wo = wbf + 4 * 16384;
#pragma unroll
    for (int it = 0; it < 4; ++it) {
        int unit = it * 512 + tid;  // 2048 units of 8 u16
        int n = unit >> 4, k8 = unit & 15;
        *(bf16x8*)&WoLds[n * 132 + k8 * 8] = *(const bf16x8*)&Wo[unit * 8];
    }
    __syncthreads();

    const int row0 = blockIdx.x * 128 + wave * 16;  // 16-row strip per wave (16 | 320)
    const int lidx = row0 / 320;
    const int irow = row0 - lidx * 320 + i_lo;

    // A-frag = O .* g (elementwise bf16; kc = head)
    bf16x8 of[4];
#pragma unroll
    for (int kc = 0; kc < 4; ++kc) {
        union { bf16x8 v; u32 u[4]; } A, G, R;
        A.v = *(const bf16x8*)&Obf[((size_t)(row0 + i_lo)) * 128 + kc * 32 + q * 8];
        G.v = *(const bf16x8*)&Gg[((size_t)((lidx * 4 + kc) * 320 + irow)) * 32 + q * 8];
#pragma unroll
        for (int k4 = 0; k4 < 4; ++k4) {
            float lo = __uint_as_float(A.u[k4] << 16) * __uint_as_float(G.u[k4] << 16);
            float hi = __uint_as_float(A.u[k4] & 0xffff0000u) * __uint_as_float(G.u[k4] & 0xffff0000u);
            R.u[k4] = pk_bf_trunc(hi, lo);
        }
        of[kc] = R.v;
    }

    f32x4 acc[8];
#pragma unroll
    for (int nt = 0; nt < 8; ++nt) acc[nt] = (f32x4){0.f, 0.f, 0.f, 0.f};
#pragma unroll
    for (int nt = 0; nt < 8; ++nt) {
#pragma unroll
        for (int kc = 0; kc < 4; ++kc) {
            bf16x8 wf = *(const bf16x8*)&WoLds[(nt * 16 + i_lo) * 132 + kc * 32 + q * 8];
            acc[nt] = __builtin_amdgcn_mfma_f32_16x16x32_bf16(wf, of[kc], acc[nt], 0, 0, 0);
        }
    }
    // lane holds out[row = row0+i_lo][col = nt*16 + q*4 + r] -> f32x4
#pragma unroll
    for (int nt = 0; nt < 8; ++nt) {
        size_t idx = ((size_t)(row0 + i_lo)) * 128 + nt * 16 + q * 4;
        f32x4 p4 = *(const f32x4*)&pair[idx];
        f32x4 b4 = *(const f32x4*)&bo[nt * 16 + q * 4];
        f32x4 o4;
        o4[0] = acc[nt][0] + p4[0] + b4[0];
        o4[1] = acc[nt][1] + p4[1] + b4[1];
        o4[2] = acc[nt][2] + p4[2] + b4[2];
        o4[3] = acc[nt][3] + p4[3] + b4[3];
        *(f32x4*)&out[idx] = o4;
    }
}

extern "C" void kernel_launch(void* const* d_in, const int* in_sizes, int n_in,
                              void* d_out, int out_size, void* d_ws, size_t ws_size,
                              hipStream_t stream) {
    const float* pair   = (const float*)d_in[0];
    const float* norm_w = (const float*)d_in[1];
    const float* norm_b = (const float*)d_in[2];
    const float* Wq     = (const float*)d_in[3];
    const float* Wk     = (const float*)d_in[4];
    const float* Wv     = (const float*)d_in[5];
    const float* Wg     = (const float*)d_in[6];
    const float* bg     = (const float*)d_in[7];
    const float* Wo     = (const float*)d_in[8];
    const float* bo     = (const float*)d_in[9];
    const float* Wb     = (const float*)d_in[10];

    u16* wbf    = (u16*)d_ws;                   // 5 * 128*128 bf16 weights
    float* cvec = (float*)(wbf + 5 * 16384);    // 512 f32 folded biases
    u16* Obf    = (u16*)(cvec + 512);           // 102400 x 128 bf16 (ungated, normalized)
    u16* Gg     = Obf + (size_t)102400 * 128;   // (l,h,i,d) 1280 x 320 x 32 bf16 gates
    float* out  = (float*)d_out;

    wconv_kernel<<<68, 256, 0, stream>>>(Wq, Wk, Wv, Wg, Wo, norm_w, norm_b, bg, wbf, cvec);
    attn_kernel<<<320 * 4, 512, 0, stream>>>(pair, Wb, wbf, cvec, Obf, Gg);
    outproj_kernel<<<800, 512, 0, stream>>>(pair, bo, Obf, Gg, wbf, out);
}